// Round 6
// baseline (232.182 us; speedup 1.0000x reference)
//
#include <hip/hip_runtime.h>

#define THRESH 0.7f

typedef float v4f __attribute__((ext_vector_type(4)));
typedef float v2f __attribute__((ext_vector_type(2)));

// Persistent grid-stride: 2048 blocks (8/CU, 100% occupancy), each thread
// iterates 8x over the lane-contiguous R1 body. Tests whether workgroup
// churn (not stream mix / ILP) is the ~2.3 TB/s limiter.
__global__ __launch_bounds__(256) void rnet_post_kernel(
    const v2f* __restrict__ cls2,   // [M] (bg, face)
    const v4f* __restrict__ reg,    // [M]
    const v4f* __restrict__ rects,  // [M]
    const int* __restrict__ hptr,
    const int* __restrict__ wptr,
    v4f*   __restrict__ out_rects,  // [M]
    float* __restrict__ out_scores, // [M]
    float* __restrict__ out_keep,   // [M]
    int M, int T)                   // T = total threads
{
    const float fh = (float)*hptr;
    const float fw = (float)*wptr;

    for (int i = blockIdx.x * blockDim.x + threadIdx.x; i < M; i += T) {
        v2f c = cls2[i];
        v4f r = rects[i];
        v4f d = reg[i];

        float score = c.y;
        float keep = (score > THRESH) ? 1.0f : 0.0f;
        float w = r.z - r.x;
        float h = r.w - r.y;
        v4f o;
        o.x = fminf(fmaxf(fmaf(d.x, w, r.x), 0.0f), fw) * keep;
        o.y = fminf(fmaxf(fmaf(d.y, h, r.y), 0.0f), fh) * keep;
        o.z = fminf(fmaxf(fmaf(d.z, w, r.z), 0.0f), fw) * keep;
        o.w = fminf(fmaxf(fmaf(d.w, h, r.w), 0.0f), fh) * keep;

        out_rects[i]  = o;
        out_scores[i] = score * keep;
        out_keep[i]   = keep;
    }
}

extern "C" void kernel_launch(void* const* d_in, const int* in_sizes, int n_in,
                              void* d_out, int out_size, void* d_ws, size_t ws_size,
                              hipStream_t stream) {
    const v2f* cls2  = (const v2f*)d_in[0];  // classifier [B,N,2]
    const v4f* reg   = (const v4f*)d_in[1];  // bbox_regress [B,N,4]
    const v4f* rects = (const v4f*)d_in[2];  // input_rects [B,N,4]
    const int* hptr  = (const int*)d_in[3];
    const int* wptr  = (const int*)d_in[4];

    const int M = in_sizes[0] / 2;  // B*N = 4,194,304

    float* out = (float*)d_out;
    v4f*   out_rects  = (v4f*)out;        // 4*M floats
    float* out_scores = out + 4ll * M;    // M floats
    float* out_keep   = out + 5ll * M;    // M floats

    const int block = 256;
    const int grid = 2048;                // 8 blocks/CU x 256 CU -> 32 waves/CU
    rnet_post_kernel<<<grid, block, 0, stream>>>(cls2, reg, rects, hptr, wptr,
                                                 out_rects, out_scores, out_keep,
                                                 M, grid * block);
}